// Round 11
// baseline (796.447 us; speedup 1.0000x reference)
//
#include <hip/hip_runtime.h>
#include <hip/hip_fp16.h>
#include <hip/hip_cooperative_groups.h>

namespace cg = cooperative_groups;

#define T_LEN 16384
#define B_SZ  256
#define S_CH  256                // time chunks per direction
#define CL    (T_LEN / S_CH)     // 64 stored steps per chunk
#define HALO  64                 // burn-in steps (contractive recurrence)
#define SC    16                 // superchunk steps (SC=32 overflows vmcnt)

__device__ __forceinline__ float ex2(float x)  { return __builtin_amdgcn_exp2f(x); }
__device__ __forceinline__ float rcpf(float x) { return __builtin_amdgcn_rcpf(x); }

__device__ __forceinline__ float ld_cvt(const float* p)  { return *p; }
__device__ __forceinline__ float ld_cvt(const __half* p) { return __half2float(*p); }
__device__ __forceinline__ void  st_cvt(float* p, float v)  { *p = v; }
__device__ __forceinline__ void  st_cvt(__half* p, float v) { *p = __float2half_rn(v); }

// One GRU step, H=1. UR,UZ pre-scaled by -log2e; UN2,DN2 by +2log2e.
__device__ __forceinline__ float gru_step(float h, float preR, float preZ, float preN,
                                          float UR, float UZ, float UN2, float DN2)
{
    float er  = ex2(fmaf(h, UR, preR));
    float ez  = ex2(fmaf(h, UZ, preZ));
    float r   = rcpf(1.0f + er);
    float z   = rcpf(1.0f + ez);
    float hn2 = fmaf(h, UN2, DN2);                    // off critical path
    float en  = ex2(fmaf(r, hn2, preN));
    float n   = fmaf(-2.0f, rcpf(1.0f + en), 1.0f);   // tanh via exp2
    float omz = 1.0f - z;
    float zh  = z * h;
    return fmaf(n, omz, zh);
}

// ---- Layer 0 scan: reads x[b][t] directly (lane owns its batch row) ----
template<bool REV>
__device__ void scan0(const float* __restrict__ x,
                      const float* __restrict__ wih, const float* __restrict__ whh,
                      const float* __restrict__ bih, const float* __restrict__ bhh,
                      __half* __restrict__ out, int b, int s)
{
    const int d = REV ? 1 : 0;
    const float L2E = 1.4426950408889634f;
    const float WR  = -L2E * wih[d*3+0];
    const float WZ  = -L2E * wih[d*3+1];
    const float WN  =  2.0f*L2E * wih[d*3+2];
    const float UR  = -L2E * whh[d*3+0];
    const float UZ  = -L2E * whh[d*3+1];
    const float UN2 =  2.0f*L2E * whh[d*3+2];
    const float CR  = -L2E * (bih[d*3+0] + bhh[d*3+0]);
    const float CZ  = -L2E * (bih[d*3+1] + bhh[d*3+1]);
    const float CN  =  2.0f*L2E * bih[d*3+2];
    const float DN2 =  2.0f*L2E * bhh[d*3+2];

    const int warm   = min(HALO, REV ? (T_LEN - (s + 1) * CL) : (s * CL));
    const int nsteps = warm + CL;           // {64,128}: nsup always even
    const int t0     = REV ? ((s + 1) * CL - 1 + warm) : (s * CL - warm);

    const float* row = x + (size_t)b * T_LEN;
    __half* po = out + (REV ? B_SZ : 0) + b;   // [t][2][b]

    float xA[SC], xB[SC];
    float h = 0.0f;

    auto LD = [&](float* F, int base) {
        const float4* p = (const float4*)(row + (REV ? (t0 - base - 15) : (t0 + base)));
        float4 v0 = p[0], v1 = p[1], v2 = p[2], v3 = p[3];
        float lin[16] = { v0.x,v0.y,v0.z,v0.w, v1.x,v1.y,v1.z,v1.w,
                          v2.x,v2.y,v2.z,v2.w, v3.x,v3.y,v3.z,v3.w };
        #pragma unroll
        for (int k = 0; k < 16; ++k) F[k] = REV ? lin[15 - k] : lin[k];
        __builtin_amdgcn_sched_barrier(0);
    };

    auto CS = [&](float* F, int base) {
        float ov[SC];
        #pragma unroll
        for (int k = 0; k < SC; ++k) {
            float xv = F[k];
            h = gru_step(h, fmaf(xv, WR, CR), fmaf(xv, WZ, CZ), fmaf(xv, WN, CN),
                         UR, UZ, UN2, DN2);
            ov[k] = h;
        }
        if (base >= warm) {
            #pragma unroll
            for (int k = 0; k < SC; ++k) {
                int t = REV ? (t0 - (base + k)) : (t0 + (base + k));
                st_cvt(po + t * (2 * B_SZ), ov[k]);
            }
        }
    };

    LD(xA, 0);
    const int nsup = nsteps / SC;
    for (int i = 0; i < nsup; i += 2) {
        LD(xB, min((i + 1) * SC, nsteps - SC));
        CS(xA, i * SC);
        LD(xA, min((i + 2) * SC, nsteps - SC));
        CS(xB, (i + 1) * SC);
    }
}

// ------------- Layers 1/2 scan: in[t][2][b] TIN -> out[t][2][b] TOUT -------------
template<bool REV, typename TIN, typename TOUT>
__device__ void scan12(const TIN* __restrict__ in,
                       const float* __restrict__ wih, const float* __restrict__ whh,
                       const float* __restrict__ bih, const float* __restrict__ bhh,
                       TOUT* __restrict__ out, int b, int s)
{
    const int d = REV ? 1 : 0;
    const float L2E = 1.4426950408889634f;
    const float WR0 = -L2E * wih[(d*3+0)*2+0], WR1 = -L2E * wih[(d*3+0)*2+1];
    const float WZ0 = -L2E * wih[(d*3+1)*2+0], WZ1 = -L2E * wih[(d*3+1)*2+1];
    const float WN0 =  2.0f*L2E * wih[(d*3+2)*2+0], WN1 = 2.0f*L2E * wih[(d*3+2)*2+1];
    const float UR  = -L2E * whh[d*3+0];
    const float UZ  = -L2E * whh[d*3+1];
    const float UN2 =  2.0f*L2E * whh[d*3+2];
    const float CR  = -L2E * (bih[d*3+0] + bhh[d*3+0]);
    const float CZ  = -L2E * (bih[d*3+1] + bhh[d*3+1]);
    const float CN  =  2.0f*L2E * bih[d*3+2];
    const float DN2 =  2.0f*L2E * bhh[d*3+2];

    const int warm   = min(HALO, REV ? (T_LEN - (s + 1) * CL) : (s * CL));
    const int nsteps = warm + CL;
    const int t0     = REV ? ((s + 1) * CL - 1 + warm) : (s * CL - warm);

    const TIN* pf = in + b;                 // fwd stream
    const TIN* pg = in + B_SZ + b;          // bwd stream
    TOUT* po = out + (REV ? B_SZ : 0) + b;

    float fA[SC], gA[SC], fB[SC], gB[SC];
    float h = 0.0f;

#define LD12(F, G, base_) { int base = (base_); \
    _Pragma("unroll") for (int k = 0; k < SC; ++k) { \
      int t = REV ? (t0 - (base + k)) : (t0 + (base + k)); \
      F[k] = ld_cvt(pf + t * (2 * B_SZ)); G[k] = ld_cvt(pg + t * (2 * B_SZ)); } \
    __builtin_amdgcn_sched_barrier(0); }

#define CS12(F, G, base_) { int base = (base_); float ov[SC]; \
    _Pragma("unroll") for (int k = 0; k < SC; ++k) { \
      float a = F[k], c = G[k]; \
      float pr = fmaf(a, WR0, fmaf(c, WR1, CR)); \
      float pz = fmaf(a, WZ0, fmaf(c, WZ1, CZ)); \
      float pn = fmaf(a, WN0, fmaf(c, WN1, CN)); \
      h = gru_step(h, pr, pz, pn, UR, UZ, UN2, DN2); ov[k] = h; } \
    if (base >= warm) { \
      _Pragma("unroll") for (int k = 0; k < SC; ++k) { \
        int t = REV ? (t0 - (base + k)) : (t0 + (base + k)); \
        st_cvt(po + t * (2 * B_SZ), ov[k]); } } }

    LD12(fA, gA, 0);
    const int nsup = nsteps / SC;
    for (int i = 0; i < nsup; i += 2) {
        LD12(fB, gB, min((i + 1) * SC, nsteps - SC));
        CS12(fA, gA, i * SC);
        LD12(fA, gA, min((i + 2) * SC, nsteps - SC));
        CS12(fB, gB, (i + 1) * SC);
    }
#undef LD12
#undef CS12
}

// XCD swizzle: xcd = blk&7 owns chunks [xcd*32, xcd*32+32) -> halo L2-local.
__device__ __forceinline__ void decode_blk(int blk, int tid, int& b, int& s, int& dir)
{
    int xcd = blk & 7;
    int j   = blk >> 3;            // 0..255
    int sl  = j & 31;
    int bg  = (j >> 5) & 3;
    dir     = j >> 7;
    s       = xcd * 32 + sl;
    b       = bg * 64 + tid;
}

// proj tile (64 threads): y[b][t] = wf*h2[t][0][b] + wb*h2[t][1][b] + bias
__device__ void proj_tile(const float* __restrict__ h2, const float* __restrict__ wo,
                          const float* __restrict__ bo, float* __restrict__ y,
                          int tile_id, int tid)
{
    __shared__ float tile[64][65];          // [b_local][t_local]
    const int b0 = (tile_id & 3) * 64;
    const int t0 = (tile_id >> 2) * 64;
    const float wf = wo[0], wb = wo[1], bias = bo[0];
    for (int tl = 0; tl < 64; ++tl) {
        int t = t0 + tl;
        float f = h2[(size_t)t * (2 * B_SZ) + b0 + tid];
        float g = h2[(size_t)t * (2 * B_SZ) + B_SZ + b0 + tid];
        tile[tid][tl] = fmaf(wf, f, fmaf(wb, g, bias));
    }
    __syncthreads();
    const int c4 = tid & 15;
    const int r0 = tid >> 4;                // 0..3
    #pragma unroll
    for (int i = 0; i < 16; ++i) {
        int brow = r0 + 4 * i;
        float4 v = make_float4(tile[brow][c4*4+0], tile[brow][c4*4+1],
                               tile[brow][c4*4+2], tile[brow][c4*4+3]);
        ((float4*)y)[(size_t)(b0 + brow) * (T_LEN / 4) + t0 / 4 + c4] = v;
    }
}

struct FusedArgs {
    const float* x;
    const float* w_ih0; const float* w_hh0; const float* b_ih0; const float* b_hh0;
    const float* w_ih12; const float* w_hh12; const float* b_ih12; const float* b_hh12;
    const float* w_out; const float* b_out;
    __half* l0out; __half* l1out; float* l2out; float* y;
};

// 2048 blocks x 64 threads, cooperative. 8 blocks/CU co-resident
// (launch_bounds caps VGPR<=256 -> 8 waves/CU; LDS 16.6KB*8=133KB<160KB).
__global__ void __launch_bounds__(64, 2) k_fused(FusedArgs a)
{
    cg::grid_group grid = cg::this_grid();
    int b, s, dir;
    decode_blk(blockIdx.x, threadIdx.x, b, s, dir);

    // Phase 0: layer-0 scan, x -> l0out (half)
    if (dir == 0) scan0<false>(a.x, a.w_ih0, a.w_hh0, a.b_ih0, a.b_hh0, a.l0out, b, s);
    else          scan0<true >(a.x, a.w_ih0, a.w_hh0, a.b_ih0, a.b_hh0, a.l0out, b, s);
    grid.sync();

    // Phase 1: layer-1 scan, l0out -> l1out (half)
    if (dir == 0) scan12<false>(a.l0out, a.w_ih12 + 0, a.w_hh12 + 0, a.b_ih12 + 0, a.b_hh12 + 0, a.l1out, b, s);
    else          scan12<true >(a.l0out, a.w_ih12 + 0, a.w_hh12 + 0, a.b_ih12 + 0, a.b_hh12 + 0, a.l1out, b, s);
    grid.sync();

    // Phase 2: layer-2 scan, l1out -> l2out (fp32)
    if (dir == 0) scan12<false>(a.l1out, a.w_ih12 + 12, a.w_hh12 + 6, a.b_ih12 + 6, a.b_hh12 + 6, a.l2out, b, s);
    else          scan12<true >(a.l1out, a.w_ih12 + 12, a.w_hh12 + 6, a.b_ih12 + 6, a.b_hh12 + 6, a.l2out, b, s);
    grid.sync();

    // Phase 3: projection + transpose back (1024 tiles; blocks 0..1023)
    if (blockIdx.x < 1024)
        proj_tile(a.l2out, a.w_out, a.b_out, a.y, blockIdx.x, threadIdx.x);
}

extern "C" void kernel_launch(void* const* d_in, const int* in_sizes, int n_in,
                              void* d_out, int out_size, void* d_ws, size_t ws_size,
                              hipStream_t stream)
{
    (void)in_sizes; (void)n_in; (void)out_size; (void)ws_size;

    char* ws = (char*)d_ws;
    const size_t NN = (size_t)2 * B_SZ * T_LEN;   // elements per [t][2][b] buffer

    FusedArgs a;
    a.x      = (const float*)d_in[0];
    a.w_ih0  = (const float*)d_in[1];
    a.w_hh0  = (const float*)d_in[2];
    a.b_ih0  = (const float*)d_in[3];
    a.b_hh0  = (const float*)d_in[4];
    a.w_ih12 = (const float*)d_in[5];
    a.w_hh12 = (const float*)d_in[6];
    a.b_ih12 = (const float*)d_in[7];
    a.b_hh12 = (const float*)d_in[8];
    a.w_out  = (const float*)d_in[9];
    a.b_out  = (const float*)d_in[10];
    a.l0out  = (__half*)ws;                 // 16.8 MB
    a.l1out  = (__half*)(ws + NN * 2);      // 16.8 MB
    a.l2out  = (float*)(ws + NN * 4);       // 33.5 MB
    a.y      = (float*)d_out;

    void* params[] = { &a };
    hipLaunchCooperativeKernel((const void*)k_fused, dim3(2048), dim3(64),
                               params, 0, stream);
}

// Round 12
// 136.538 us; speedup vs baseline: 5.8332x; 5.8332x over previous
//
#include <hip/hip_runtime.h>
#include <hip/hip_fp16.h>

#define T_LEN 16384
#define B_SZ  256
#define S_CH  256                // time chunks per direction
#define CL    (T_LEN / S_CH)     // 64 stored steps per chunk
#define HALO  32                 // burn-in steps (contractive recurrence)
#define SC    16                 // superchunk steps (SC=32 overflows vmcnt)

__device__ __forceinline__ float ex2(float x)  { return __builtin_amdgcn_exp2f(x); }
__device__ __forceinline__ float rcpf(float x) { return __builtin_amdgcn_rcpf(x); }

__device__ __forceinline__ float ld_cvt(const float* p)  { return *p; }
__device__ __forceinline__ float ld_cvt(const __half* p) { return __half2float(*p); }
__device__ __forceinline__ void  st_cvt(float* p, float v)  { *p = v; }
__device__ __forceinline__ void  st_cvt(__half* p, float v) { *p = __float2half_rn(v); }

// One GRU step, H=1. UR,UZ pre-scaled by -log2e; UN2,DN2 by +2log2e.
__device__ __forceinline__ float gru_step(float h, float preR, float preZ, float preN,
                                          float UR, float UZ, float UN2, float DN2)
{
    float er  = ex2(fmaf(h, UR, preR));
    float ez  = ex2(fmaf(h, UZ, preZ));
    float r   = rcpf(1.0f + er);
    float z   = rcpf(1.0f + ez);
    float hn2 = fmaf(h, UN2, DN2);                    // off critical path
    float en  = ex2(fmaf(r, hn2, preN));
    float n   = fmaf(-2.0f, rcpf(1.0f + en), 1.0f);   // tanh via exp2
    float omz = 1.0f - z;
    float zh  = z * h;
    return fmaf(n, omz, zh);
}

// ---- Layer 0 scan: reads x[b][t] DIRECTLY (lane owns its batch row; 4 strided
// ---- float4 loads per 16-step superchunk; each lane consumes its full line).
// ---- Writes out[t][2][b] half (dense 128B stores per dir).
template<bool REV>
__device__ void scan0(const float* __restrict__ x,
                      const float* __restrict__ wih, const float* __restrict__ whh,
                      const float* __restrict__ bih, const float* __restrict__ bhh,
                      __half* __restrict__ out, int b, int s)
{
    const int d = REV ? 1 : 0;
    const float L2E = 1.4426950408889634f;
    const float WR  = -L2E * wih[d*3+0];
    const float WZ  = -L2E * wih[d*3+1];
    const float WN  =  2.0f*L2E * wih[d*3+2];
    const float UR  = -L2E * whh[d*3+0];
    const float UZ  = -L2E * whh[d*3+1];
    const float UN2 =  2.0f*L2E * whh[d*3+2];
    const float CR  = -L2E * (bih[d*3+0] + bhh[d*3+0]);
    const float CZ  = -L2E * (bih[d*3+1] + bhh[d*3+1]);
    const float CN  =  2.0f*L2E * bih[d*3+2];
    const float DN2 =  2.0f*L2E * bhh[d*3+2];

    const int warm   = min(HALO, REV ? (T_LEN - (s + 1) * CL) : (s * CL));
    const int nsteps = warm + CL;           // {64,96}: nsup in {4,6}, always even
    const int t0     = REV ? ((s + 1) * CL - 1 + warm) : (s * CL - warm);

    const float* row = x + (size_t)b * T_LEN;
    __half* po = out + (REV ? B_SZ : 0) + b;   // [t][2][b]

    float xA[SC], xB[SC];
    float h = 0.0f;

    auto LD = [&](float* F, int base) {
        // fwd: window [t0+base, t0+base+16); rev: [t0-base-15, t0-base+1)
        const float4* p = (const float4*)(row + (REV ? (t0 - base - 15) : (t0 + base)));
        float4 v0 = p[0], v1 = p[1], v2 = p[2], v3 = p[3];
        float lin[16] = { v0.x,v0.y,v0.z,v0.w, v1.x,v1.y,v1.z,v1.w,
                          v2.x,v2.y,v2.z,v2.w, v3.x,v3.y,v3.z,v3.w };
        #pragma unroll
        for (int k = 0; k < 16; ++k) F[k] = REV ? lin[15 - k] : lin[k];
        __builtin_amdgcn_sched_barrier(0);
    };

    auto CS = [&](float* F, int base) {
        float ov[SC];
        #pragma unroll
        for (int k = 0; k < SC; ++k) {
            float xv = F[k];
            h = gru_step(h, fmaf(xv, WR, CR), fmaf(xv, WZ, CZ), fmaf(xv, WN, CN),
                         UR, UZ, UN2, DN2);
            ov[k] = h;
        }
        if (base >= warm) {
            #pragma unroll
            for (int k = 0; k < SC; ++k) {
                int t = REV ? (t0 - (base + k)) : (t0 + (base + k));
                st_cvt(po + t * (2 * B_SZ), ov[k]);
            }
        }
    };

    LD(xA, 0);
    const int nsup = nsteps / SC;
    for (int i = 0; i < nsup; i += 2) {
        LD(xB, min((i + 1) * SC, nsteps - SC));
        CS(xA, i * SC);
        LD(xA, min((i + 2) * SC, nsteps - SC));
        CS(xB, (i + 1) * SC);
    }
}

// ------------- Layers 1/2 scan: in[t][2][b] TIN -> out[t][2][b] TOUT -------------
template<bool REV, typename TIN, typename TOUT>
__device__ void scan12(const TIN* __restrict__ in,
                       const float* __restrict__ wih, const float* __restrict__ whh,
                       const float* __restrict__ bih, const float* __restrict__ bhh,
                       TOUT* __restrict__ out, int b, int s)
{
    const int d = REV ? 1 : 0;
    const float L2E = 1.4426950408889634f;
    const float WR0 = -L2E * wih[(d*3+0)*2+0], WR1 = -L2E * wih[(d*3+0)*2+1];
    const float WZ0 = -L2E * wih[(d*3+1)*2+0], WZ1 = -L2E * wih[(d*3+1)*2+1];
    const float WN0 =  2.0f*L2E * wih[(d*3+2)*2+0], WN1 = 2.0f*L2E * wih[(d*3+2)*2+1];
    const float UR  = -L2E * whh[d*3+0];
    const float UZ  = -L2E * whh[d*3+1];
    const float UN2 =  2.0f*L2E * whh[d*3+2];
    const float CR  = -L2E * (bih[d*3+0] + bhh[d*3+0]);
    const float CZ  = -L2E * (bih[d*3+1] + bhh[d*3+1]);
    const float CN  =  2.0f*L2E * bih[d*3+2];
    const float DN2 =  2.0f*L2E * bhh[d*3+2];

    const int warm   = min(HALO, REV ? (T_LEN - (s + 1) * CL) : (s * CL));
    const int nsteps = warm + CL;
    const int t0     = REV ? ((s + 1) * CL - 1 + warm) : (s * CL - warm);

    const TIN* pf = in + b;                 // fwd stream
    const TIN* pg = in + B_SZ + b;          // bwd stream
    TOUT* po = out + (REV ? B_SZ : 0) + b;

    float fA[SC], gA[SC], fB[SC], gB[SC];
    float h = 0.0f;

#define LD12(F, G, base_) { int base = (base_); \
    _Pragma("unroll") for (int k = 0; k < SC; ++k) { \
      int t = REV ? (t0 - (base + k)) : (t0 + (base + k)); \
      F[k] = ld_cvt(pf + t * (2 * B_SZ)); G[k] = ld_cvt(pg + t * (2 * B_SZ)); } \
    __builtin_amdgcn_sched_barrier(0); }

#define CS12(F, G, base_) { int base = (base_); float ov[SC]; \
    _Pragma("unroll") for (int k = 0; k < SC; ++k) { \
      float a = F[k], c = G[k]; \
      float pr = fmaf(a, WR0, fmaf(c, WR1, CR)); \
      float pz = fmaf(a, WZ0, fmaf(c, WZ1, CZ)); \
      float pn = fmaf(a, WN0, fmaf(c, WN1, CN)); \
      h = gru_step(h, pr, pz, pn, UR, UZ, UN2, DN2); ov[k] = h; } \
    if (base >= warm) { \
      _Pragma("unroll") for (int k = 0; k < SC; ++k) { \
        int t = REV ? (t0 - (base + k)) : (t0 + (base + k)); \
        st_cvt(po + t * (2 * B_SZ), ov[k]); } } }

    LD12(fA, gA, 0);
    const int nsup = nsteps / SC;
    for (int i = 0; i < nsup; i += 2) {
        LD12(fB, gB, min((i + 1) * SC, nsteps - SC));
        CS12(fA, gA, i * SC);
        LD12(fA, gA, min((i + 2) * SC, nsteps - SC));
        CS12(fB, gB, (i + 1) * SC);
    }
#undef LD12
#undef CS12
}

// 2048 blocks. XCD swizzle: xcd = blk&7 owns chunks [xcd*32, xcd*32+32) for
// both dirs & all batch groups -> halo re-reads stay in that XCD's 4MB L2.
__device__ __forceinline__ void decode_blk(int blk, int tid, int& b, int& s, int& dir)
{
    int xcd = blk & 7;
    int j   = blk >> 3;            // 0..255
    int sl  = j & 31;
    int bg  = (j >> 5) & 3;
    dir     = j >> 7;
    s       = xcd * 32 + sl;
    b       = bg * 64 + tid;
}

__global__ void __launch_bounds__(64) k_scan0g(const float* __restrict__ x,
                                               const float* __restrict__ wih,
                                               const float* __restrict__ whh,
                                               const float* __restrict__ bih,
                                               const float* __restrict__ bhh,
                                               __half* __restrict__ out)
{
    int b, s, dir;
    decode_blk(blockIdx.x, threadIdx.x, b, s, dir);
    if (dir == 0) scan0<false>(x, wih, whh, bih, bhh, out, b, s);
    else          scan0<true >(x, wih, whh, bih, bhh, out, b, s);
}

__global__ void __launch_bounds__(64) k_scan1g(const __half* __restrict__ in,
                                               const float* __restrict__ wih,
                                               const float* __restrict__ whh,
                                               const float* __restrict__ bih,
                                               const float* __restrict__ bhh,
                                               __half* __restrict__ out)
{
    int b, s, dir;
    decode_blk(blockIdx.x, threadIdx.x, b, s, dir);
    if (dir == 0) scan12<false>(in, wih, whh, bih, bhh, out, b, s);
    else          scan12<true >(in, wih, whh, bih, bhh, out, b, s);
}

__global__ void __launch_bounds__(64) k_scan2g(const __half* __restrict__ in,
                                               const float* __restrict__ wih,
                                               const float* __restrict__ whh,
                                               const float* __restrict__ bih,
                                               const float* __restrict__ bhh,
                                               float* __restrict__ out)
{
    int b, s, dir;
    decode_blk(blockIdx.x, threadIdx.x, b, s, dir);
    if (dir == 0) scan12<false>(in, wih, whh, bih, bhh, out, b, s);
    else          scan12<true >(in, wih, whh, bih, bhh, out, b, s);
}

// proj + transpose back: y[b][t] = wf*h2[t][0][b] + wb*h2[t][1][b] + bias
__global__ void __launch_bounds__(256) k_proj(const float* __restrict__ h2,
                                              const float* __restrict__ wo,
                                              const float* __restrict__ bo,
                                              float* __restrict__ y)
{
    __shared__ float tile[64][65];          // [b_local][t_local]
    const int b0 = (blockIdx.x & 3) * 64;
    const int t0 = (blockIdx.x >> 2) * 64;
    const float wf = wo[0], wb = wo[1], bias = bo[0];
    const int bl = threadIdx.x & 63;
    const int tg = threadIdx.x >> 6;        // 0..3
    #pragma unroll
    for (int i = 0; i < 16; ++i) {
        int tl = tg * 16 + i;
        int t  = t0 + tl;
        float f = h2[(size_t)t * (2 * B_SZ) + b0 + bl];
        float g = h2[(size_t)t * (2 * B_SZ) + B_SZ + b0 + bl];
        tile[bl][tl] = fmaf(wf, f, fmaf(wb, g, bias));
    }
    __syncthreads();
    const int c4 = threadIdx.x & 15;
    const int r  = threadIdx.x >> 4;
    #pragma unroll
    for (int i = 0; i < 4; ++i) {
        int brow = r + 16 * i;
        float4 v = make_float4(tile[brow][c4*4+0], tile[brow][c4*4+1],
                               tile[brow][c4*4+2], tile[brow][c4*4+3]);
        ((float4*)y)[(size_t)(b0 + brow) * (T_LEN / 4) + t0 / 4 + c4] = v;
    }
}

extern "C" void kernel_launch(void* const* d_in, const int* in_sizes, int n_in,
                              void* d_out, int out_size, void* d_ws, size_t ws_size,
                              hipStream_t stream)
{
    (void)in_sizes; (void)n_in; (void)out_size; (void)ws_size;
    const float* x      = (const float*)d_in[0];
    const float* w_ih0  = (const float*)d_in[1];
    const float* w_hh0  = (const float*)d_in[2];
    const float* b_ih0  = (const float*)d_in[3];
    const float* b_hh0  = (const float*)d_in[4];
    const float* w_ih12 = (const float*)d_in[5];
    const float* w_hh12 = (const float*)d_in[6];
    const float* b_ih12 = (const float*)d_in[7];
    const float* b_hh12 = (const float*)d_in[8];
    const float* w_out  = (const float*)d_in[9];
    const float* b_out  = (const float*)d_in[10];
    float* y = (float*)d_out;

    // ws layout:
    //   l0out half 16.8 MB at byte [0, 16.8M)
    //   l1out half 16.8 MB at byte [16.8M, 33.5M)
    //   l2out fp32 33.5 MB at byte [33.5M, 67.1M)
    char* ws = (char*)d_ws;
    const size_t NN = (size_t)2 * B_SZ * T_LEN;   // elements per [t][2][b] buffer
    __half* l0out = (__half*)ws;
    __half* l1out = (__half*)(ws + NN * 2);
    float*  l2out = (float*)(ws + NN * 4);

    const int nblk = 8 * S_CH;   // 2048
    k_scan0g<<<nblk, 64, 0, stream>>>(x,     w_ih0,       w_hh0,      b_ih0,      b_hh0,      l0out);
    k_scan1g<<<nblk, 64, 0, stream>>>(l0out, w_ih12 + 0,  w_hh12 + 0, b_ih12 + 0, b_hh12 + 0, l1out);
    k_scan2g<<<nblk, 64, 0, stream>>>(l1out, w_ih12 + 12, w_hh12 + 6, b_ih12 + 6, b_hh12 + 6, l2out);
    k_proj  <<<1024, 256, 0, stream>>>(l2out, w_out, b_out, y);
}